// Round 3
// baseline (796.004 us; speedup 1.0000x reference)
//
#include <hip/hip_runtime.h>
#include <hip/hip_bf16.h>
#include <math.h>

typedef __attribute__((ext_vector_type(8))) short bf16x8;
typedef __attribute__((ext_vector_type(4))) float f32x4;

#define R_TOTAL 8
#define CIN     256
#define COUT    256
#define HH      128
#define WW      128
#define BB      4
#define MTOT    (COUT * R_TOTAL)   // 2048
#define KTAPS   9

#define XSZ  (3 * 130 * 32)        // elems per xs buffer (24.96 KB)
#define ABUF (128 * 32)            // elems per A buffer  (8 KB)

// ---------------------------------------------------------------------------
// async global->LDS, 16B per lane (lane l lands at base + l*16).
// ---------------------------------------------------------------------------
__device__ __forceinline__ void g2l16(void* lds, const void* g) {
    __builtin_amdgcn_global_load_lds(
        (const __attribute__((address_space(1))) unsigned int*)g,
        (__attribute__((address_space(3))) unsigned int*)lds,
        16, 0, 0);
}

// ---------------------------------------------------------------------------
// x (B,C,H,W) fp32 -> xb (B,H,W,C) bf16 (+ one appended zero row).
// ---------------------------------------------------------------------------
__global__ __launch_bounds__(256)
void to_nhwc_bf16(const float* __restrict__ x, __hip_bfloat16* __restrict__ xb) {
    __shared__ __hip_bfloat16 t[32][33];
    const int b  = blockIdx.z;
    const int c0 = blockIdx.y * 32;
    const int p0 = blockIdx.x * 32;
    const int tx = threadIdx.x & 31;
    const int ty = threadIdx.x >> 5;
    const float* xp = x + (size_t)b * CIN * (HH * WW);
    #pragma unroll
    for (int j = 0; j < 4; ++j) {
        int c = ty * 4 + j;
        t[c][tx] = __float2bfloat16(xp[(size_t)(c0 + c) * (HH * WW) + p0 + tx]);
    }
    __syncthreads();
    __hip_bfloat16* op = xb + ((size_t)b * (HH * WW) + p0) * CIN + c0;
    #pragma unroll
    for (int j = 0; j < 4; ++j) {
        int p = ty * 4 + j;
        op[(size_t)p * CIN + tx] = t[tx][p];
    }
}

__global__ __launch_bounds__(256)
void zero_guard_row(__hip_bfloat16* __restrict__ xb) {
    // one shared zero pixel-row at row index BB*HH (WW*CIN elems)
    size_t base = (size_t)BB * HH * WW * CIN;
    int i = blockIdx.x * 256 + threadIdx.x;
    xb[base + i] = __float2bfloat16(0.0f);
}

// ---------------------------------------------------------------------------
// Rotate weights (fp32 math == jax affine_grid/grid_sample, align_corners=F,
// zero pad) -> rwb[m][tap][i] bf16, m = o*8 + r.
// ---------------------------------------------------------------------------
__global__ __launch_bounds__(256)
void rotate_weights_bf16(const float* __restrict__ w, __hip_bfloat16* __restrict__ rwb) {
    const int i = threadIdx.x;
    const int m = blockIdx.x;
    const int o = m >> 3, r = m & 7;

    float ang = 6.283185307179586f * (float)r / 8.0f;
    float cs = cosf(ang), sn = sinf(ang);

    const float* wp = w + ((size_t)o * CIN + i) * 9;
    __hip_bfloat16* op = rwb + (size_t)m * (KTAPS * CIN) + i;

    #pragma unroll
    for (int ky = 0; ky < 3; ++ky) {
        #pragma unroll
        for (int kx = 0; kx < 3; ++kx) {
            float yg = (2.0f * (float)ky + 1.0f) / 3.0f - 1.0f;
            float xg = (2.0f * (float)kx + 1.0f) / 3.0f - 1.0f;
            float xsf = cs * xg - sn * yg;
            float ysf = sn * xg + cs * yg;
            float ix = ((xsf + 1.0f) * 3.0f - 1.0f) * 0.5f;
            float iy = ((ysf + 1.0f) * 3.0f - 1.0f) * 0.5f;
            float ix0f = floorf(ix), iy0f = floorf(iy);
            float wx1 = ix - ix0f,  wy1 = iy - iy0f;
            float wx0 = 1.0f - wx1, wy0 = 1.0f - wy1;
            int ix0 = (int)ix0f, iy0 = (int)iy0f;
            int ix1 = ix0 + 1,   iy1 = iy0 + 1;
            float acc = 0.0f;
            if (iy0 >= 0 && iy0 < 3 && ix0 >= 0 && ix0 < 3) acc += wp[iy0*3+ix0] * (wy0*wx0);
            if (iy0 >= 0 && iy0 < 3 && ix1 >= 0 && ix1 < 3) acc += wp[iy0*3+ix1] * (wy0*wx1);
            if (iy1 >= 0 && iy1 < 3 && ix0 >= 0 && ix0 < 3) acc += wp[iy1*3+ix0] * (wy1*wx0);
            if (iy1 >= 0 && iy1 < 3 && ix1 >= 0 && ix1 < 3) acc += wp[iy1*3+ix1] * (wy1*wx1);
            op[(ky * 3 + kx) * CIN] = __float2bfloat16(acc);
        }
    }
}

// ---------------------------------------------------------------------------
// Main MFMA conv, counted-vmcnt schedule.
// Block tile 128(M) x 128(N = one image row), 4 waves of 64x64, 16x16x32 bf16.
// K-steps: 8 chunks(32ch) x 9 taps = 72. A 3-buffered (depth-2 prefetch),
// xs double-buffered (next-chunk X issued at taps 3..5). One raw s_barrier
// per tap with counted vmcnt — never drained to 0 in the main loop.
// ---------------------------------------------------------------------------
__global__ __launch_bounds__(256)
void rotconv_mfma_kernel(const __hip_bfloat16* __restrict__ xb,
                         const __hip_bfloat16* __restrict__ rwb,
                         float* __restrict__ out) {
    const int tid  = threadIdx.x;
    const int lane = tid & 63;
    const int w    = tid >> 6;
    const int wm   = w >> 1, wn = w & 1;
    const int q    = lane >> 4, lr = lane & 15;

    const int bid = blockIdx.x;
    const int mt  = bid >> 9;
    const int nt  = bid & 511;
    const int b   = nt >> 7;
    const int y0  = nt & 127;
    const int m0  = mt << 7;

    __shared__ __align__(16) __hip_bfloat16 xs[2 * XSZ];
    __shared__ __align__(16) __hip_bfloat16 As[3 * ABUF];

    // zero both xs buffers (covers border cols 0/129, never re-written)
    {
        int* z = (int*)xs;
        for (int j = tid; j < (2 * XSZ) / 2; j += 256) z[j] = 0;
    }

    // ---- per-thread read offsets (element units) ----
    int aOff[4];
    #pragma unroll
    for (int mi = 0; mi < 4; ++mi) {
        int row = wm * 64 + mi * 16 + lr;
        aOff[mi] = row * 32 + 8 * (q ^ ((row >> 1) & 3));
    }
    int bOff[4][3];
    #pragma unroll
    for (int ni = 0; ni < 4; ++ni)
        #pragma unroll
        for (int kx = 0; kx < 3; ++kx) {
            int colL = wn * 64 + ni * 16 + lr + kx;
            bOff[ni][kx] = colL * 32 + 8 * (q ^ ((colL >> 1) & 3));
        }

    // ---- staging bases ----
    const __hip_bfloat16* srcA0;
    const __hip_bfloat16* srcA1;
    int dstA0, dstA1;
    {
        int row0 = 0 * 64 + w * 16 + (lane >> 2);
        int row1 = 1 * 64 + w * 16 + (lane >> 2);
        dstA0 = (0 * 64 + w * 16) * 32;
        dstA1 = (1 * 64 + w * 16) * 32;
        srcA0 = rwb + (size_t)(m0 + row0) * (KTAPS * CIN) + 8 * ((lane & 3) ^ ((row0 >> 1) & 3));
        srcA1 = rwb + (size_t)(m0 + row1) * (KTAPS * CIN) + 8 * ((lane & 3) ^ ((row1 >> 1) & 3));
    }
    // X: 6 loads cover 3 rows x 128 cols x 32 ch; OOB rows clamp to the
    // shared zero row -> unconditional issue (uniform vmcnt accounting).
    const __hip_bfloat16* srcX[6];
    int dstX[6];
    #pragma unroll
    for (int it = 0; it < 6; ++it) {
        int wt = it * 4 + w;
        int rr = wt >> 3, cg = (wt & 7) * 16;
        int gy = y0 - 1 + rr;
        size_t rowIdx = ((unsigned)gy < (unsigned)HH) ? (size_t)(b * HH + gy)
                                                      : (size_t)(BB * HH);
        int gx = cg + (lane >> 2);
        int colL = gx + 1;
        dstX[it] = (rr * 130 + 1 + cg) * 32;
        srcX[it] = xb + (rowIdx * WW + gx) * CIN + 8 * ((lane & 3) ^ ((colL >> 1) & 3));
    }

    f32x4 acc[4][4];
    #pragma unroll
    for (int mi = 0; mi < 4; ++mi)
        #pragma unroll
        for (int ni = 0; ni < 4; ++ni) {
            f32x4 z = {0.f, 0.f, 0.f, 0.f};
            acc[mi][ni] = z;
        }

    __syncthreads();   // zeroing complete before async loads land

    // prologue: X(chunk0) -> xs buf0; A(tap0)->Ab0; A(tap1)->Ab1; full drain.
    #pragma unroll
    for (int j = 0; j < 6; ++j) g2l16(xs + dstX[j], srcX[j]);
    g2l16(As + 0 * ABUF + dstA0, srcA0 + 0);
    g2l16(As + 0 * ABUF + dstA1, srcA1 + 0);
    g2l16(As + 1 * ABUF + dstA0, srcA0 + CIN);
    g2l16(As + 1 * ABUF + dstA1, srcA1 + CIN);
    asm volatile("s_waitcnt vmcnt(0)" ::: "memory");
    __syncthreads();

// ---- one tap: wait(counted) -> barrier -> issue A(t+2)[, X] -> ds_read -> MFMA
#define TAP(P, NW, DOWAIT, ISSA, ISSX)                                         \
  {                                                                            \
    if (DOWAIT) { asm volatile("s_waitcnt vmcnt(%0)" :: "i"(NW) : "memory"); } \
    __builtin_amdgcn_s_barrier();                                              \
    __builtin_amdgcn_sched_barrier(0);                                         \
    if (ISSA) {                                                                \
      const int aoff = (((P) + 2) / 9) * 32 + (((P) + 2) % 9) * CIN + i0;      \
      __hip_bfloat16* ab = As + ((((P) + 2) % 3) * ABUF);                      \
      g2l16(ab + dstA0, srcA0 + aoff);                                         \
      g2l16(ab + dstA1, srcA1 + aoff);                                         \
    }                                                                          \
    if (ISSX) {                                                                \
      const int j0 = ((P) >= 3 ? 2 * ((P) - 3) : 0);                           \
      g2l16(xsW + dstX[j0],     srcX[j0]     + i1);                            \
      g2l16(xsW + dstX[j0 + 1], srcX[j0 + 1] + i1);                            \
    }                                                                          \
    const __hip_bfloat16* ar = As + (((P) % 3) * ABUF);                        \
    const __hip_bfloat16* br = xsR + (((P) / 3) * (130 * 32));                 \
    bf16x8 af[4], bfv[4];                                                      \
    _Pragma("unroll")                                                          \
    for (int mi = 0; mi < 4; ++mi) af[mi] = *(const bf16x8*)(ar + aOff[mi]);   \
    _Pragma("unroll")                                                          \
    for (int ni = 0; ni < 4; ++ni)                                             \
        bfv[ni] = *(const bf16x8*)(br + bOff[ni][(P) % 3]);                    \
    __builtin_amdgcn_s_setprio(1);                                             \
    _Pragma("unroll")                                                          \
    for (int mi = 0; mi < 4; ++mi)                                             \
        _Pragma("unroll")                                                      \
        for (int ni = 0; ni < 4; ++ni)                                         \
            acc[mi][ni] = __builtin_amdgcn_mfma_f32_16x16x32_bf16(             \
                af[mi], bfv[ni], acc[mi][ni], 0, 0, 0);                        \
    __builtin_amdgcn_s_setprio(0);                                             \
  }

// steady vmcnt table p=0..8: [2,2,2,2,4,6,6,4,2]; last chunk: [2,...,2,0]
#define CHUNK(FIRSTC, LASTC)                                                   \
  {                                                                            \
    const int i0 = c * 32;                                                     \
    const int i1 = i0 + 32;                                                    \
    const __hip_bfloat16* xsR = xs + (c & 1) * XSZ;                            \
    __hip_bfloat16* xsW = xs + ((c + 1) & 1) * XSZ;                            \
    (void)xsW; (void)i1;                                                       \
    TAP(0, 2, !(FIRSTC), 1, 0)                                                 \
    TAP(1, 2, 1, 1, 0)                                                         \
    TAP(2, 2, 1, 1, 0)                                                         \
    TAP(3, 2, 1, 1, !(LASTC))                                                  \
    TAP(4, ((LASTC) ? 2 : 4), 1, 1, !(LASTC))                                  \
    TAP(5, ((LASTC) ? 2 : 6), 1, 1, !(LASTC))                                  \
    TAP(6, ((LASTC) ? 2 : 6), 1, 1, 0)                                         \
    TAP(7, ((LASTC) ? 2 : 4), 1, !(LASTC), 0)                                  \
    TAP(8, ((LASTC) ? 0 : 2), 1, !(LASTC), 0)                                  \
  }

    { const int c = 0; CHUNK(1, 0) }
    for (int c = 1; c < 7; ++c) CHUNK(0, 0)
    { const int c = 7; CHUNK(0, 1) }

#undef TAP
#undef CHUNK

    // epilogue: max over 8 rotations (4 regs + quarter-swap), write fp32
    const int oBase = (m0 + wm * 64) >> 3;
    #pragma unroll
    for (int mi = 0; mi < 4; ++mi) {
        #pragma unroll
        for (int ni = 0; ni < 4; ++ni) {
            f32x4 a4 = acc[mi][ni];
            float v = fmaxf(fmaxf(a4[0], a4[1]), fmaxf(a4[2], a4[3]));
            v = fmaxf(v, __shfl_xor(v, 16));
            if ((q & 1) == 0) {
                int o = oBase + mi * 2 + (q >> 1);
                int xcol = wn * 64 + ni * 16 + lr;
                out[(((size_t)(b * COUT + o)) * HH + y0) * WW + xcol] = v;
            }
        }
    }
}

// ===========================================================================
// Fallback fp32 path (round-0, known-correct) in case ws is too small.
// ===========================================================================
__global__ void rotate_weights_kernel(const float* __restrict__ w,
                                      float* __restrict__ rw,
                                      int r0, int rcount) {
    int idx = blockIdx.x * blockDim.x + threadIdx.x;
    int total = COUT * CIN * rcount;
    if (idx >= total) return;
    int rr = idx % rcount;
    int ii = (idx / rcount) % CIN;
    int oo = idx / (rcount * CIN);
    int r  = r0 + rr;
    float ang = 6.283185307179586f * (float)r / 8.0f;
    float cs = cosf(ang), sn = sinf(ang);
    const float* wp = w  + ((size_t)oo * CIN + ii) * 9;
    float*       op = rw + (((size_t)oo * CIN + ii) * rcount + rr) * 9;
    #pragma unroll
    for (int ky = 0; ky < 3; ++ky)
        #pragma unroll
        for (int kx = 0; kx < 3; ++kx) {
            float yg = (2.0f * ky + 1.0f) / 3.0f - 1.0f;
            float xg = (2.0f * kx + 1.0f) / 3.0f - 1.0f;
            float xsf = cs * xg - sn * yg;
            float ysf = sn * xg + cs * yg;
            float ix = ((xsf + 1.0f) * 3.0f - 1.0f) * 0.5f;
            float iy = ((ysf + 1.0f) * 3.0f - 1.0f) * 0.5f;
            float ix0f = floorf(ix), iy0f = floorf(iy);
            float wx1 = ix - ix0f,  wy1 = iy - iy0f;
            float wx0 = 1.0f - wx1, wy0 = 1.0f - wy1;
            int ix0 = (int)ix0f, iy0 = (int)iy0f;
            int ix1 = ix0 + 1,   iy1 = iy0 + 1;
            float acc = 0.0f;
            if (iy0 >= 0 && iy0 < 3 && ix0 >= 0 && ix0 < 3) acc += wp[iy0*3+ix0]*(wy0*wx0);
            if (iy0 >= 0 && iy0 < 3 && ix1 >= 0 && ix1 < 3) acc += wp[iy0*3+ix1]*(wy0*wx1);
            if (iy1 >= 0 && iy1 < 3 && ix0 >= 0 && ix0 < 3) acc += wp[iy1*3+ix0]*(wy1*wx0);
            if (iy1 >= 0 && iy1 < 3 && ix1 >= 0 && ix1 < 3) acc += wp[iy1*3+ix1]*(wy1*wx1);
            op[ky * 3 + kx] = acc;
        }
}

template <int RCOUNT>
__global__ __launch_bounds__(256)
void rotconv_max_kernel(const float* __restrict__ x,
                        const float* __restrict__ rw,
                        float* __restrict__ out,
                        int first) {
    const int tid = threadIdx.x;
    const int tx = tid & 15;
    const int ty = tid >> 4;
    const int x0 = blockIdx.x * 32;
    const int y0 = blockIdx.y * 32;
    const int o  = blockIdx.z % COUT;
    const int b  = blockIdx.z / COUT;
    __shared__ float xsm[34][36];
    float acc[RCOUNT][2][2];
    #pragma unroll
    for (int r = 0; r < RCOUNT; ++r)
        #pragma unroll
        for (int py = 0; py < 2; ++py)
            #pragma unroll
            for (int px = 0; px < 2; ++px) acc[r][py][px] = 0.0f;
    for (int i = 0; i < CIN; ++i) {
        __syncthreads();
        const float* xp = x + ((size_t)(b * CIN + i)) * (HH * WW);
        for (int idx = tid; idx < 34 * 34; idx += 256) {
            int row = idx / 34, col = idx - row * 34;
            int gy = y0 - 1 + row, gx = x0 - 1 + col;
            float v = 0.0f;
            if (gy >= 0 && gy < HH && gx >= 0 && gx < WW) v = xp[gy * WW + gx];
            xsm[row][col] = v;
        }
        __syncthreads();
        float xv[4][4];
        #pragma unroll
        for (int ry = 0; ry < 4; ++ry)
            #pragma unroll
            for (int cx = 0; cx < 4; ++cx) xv[ry][cx] = xsm[ty*2+ry][tx*2+cx];
        const float* wp = rw + ((size_t)(o * CIN + i)) * (RCOUNT * 9);
        #pragma unroll
        for (int r = 0; r < RCOUNT; ++r) {
            float wv[9];
            #pragma unroll
            for (int t2 = 0; t2 < 9; ++t2) wv[t2] = wp[r * 9 + t2];
            #pragma unroll
            for (int py = 0; py < 2; ++py)
                #pragma unroll
                for (int px = 0; px < 2; ++px) {
                    float a = acc[r][py][px];
                    #pragma unroll
                    for (int ky = 0; ky < 3; ++ky)
                        #pragma unroll
                        for (int kx = 0; kx < 3; ++kx)
                            a += xv[py+ky][px+kx] * wv[ky*3+kx];
                    acc[r][py][px] = a;
                }
        }
    }
    #pragma unroll
    for (int py = 0; py < 2; ++py)
        #pragma unroll
        for (int px = 0; px < 2; ++px) {
            float m = acc[0][py][px];
            #pragma unroll
            for (int r = 1; r < RCOUNT; ++r) m = fmaxf(m, acc[r][py][px]);
            int oy = y0 + ty * 2 + py;
            int ox = x0 + tx * 2 + px;
            float* op = out + (((size_t)(b * COUT + o)) * HH + oy) * WW + ox;
            if (first) *op = m;
            else       *op = fmaxf(*op, m);
        }
}

// ===========================================================================
extern "C" void kernel_launch(void* const* d_in, const int* in_sizes, int n_in,
                              void* d_out, int out_size, void* d_ws, size_t ws_size,
                              hipStream_t stream) {
    const float* x = (const float*)d_in[0];
    const float* w = (const float*)d_in[1];
    float* out = (float*)d_out;

    const size_t xbBytes = ((size_t)BB * HH * WW + WW) * CIN * sizeof(__hip_bfloat16); // +1 zero row
    const size_t rwBytes = (size_t)MTOT * KTAPS * CIN * sizeof(__hip_bfloat16);

    if (ws_size >= xbBytes + rwBytes) {
        __hip_bfloat16* xbuf = (__hip_bfloat16*)d_ws;
        __hip_bfloat16* rwb  = (__hip_bfloat16*)((char*)d_ws + xbBytes);

        to_nhwc_bf16<<<dim3((HH * WW) / 32, CIN / 32, BB), 256, 0, stream>>>(x, xbuf);
        zero_guard_row<<<(WW * CIN) / 256, 256, 0, stream>>>(xbuf);
        rotate_weights_bf16<<<MTOT, 256, 0, stream>>>(w, rwb);
        rotconv_mfma_kernel<<<16 * 512, 256, 0, stream>>>(xbuf, rwb, out);
        return;
    }

    // ---- fallback fp32 path ----
    float* rw = (float*)d_ws;
    int chunk = 8;
    while (chunk > 1 && (size_t)COUT * CIN * chunk * 9 * sizeof(float) > ws_size)
        chunk >>= 1;
    int first = 1;
    for (int r0 = 0; r0 < R_TOTAL; r0 += chunk) {
        int rc = chunk;
        int total = COUT * CIN * rc;
        rotate_weights_kernel<<<(total + 255) / 256, 256, 0, stream>>>(w, rw, r0, rc);
        dim3 grid(WW / 32, HH / 32, BB * COUT);
        switch (rc) {
            case 8: rotconv_max_kernel<8><<<grid, 256, 0, stream>>>(x, rw, out, first); break;
            case 4: rotconv_max_kernel<4><<<grid, 256, 0, stream>>>(x, rw, out, first); break;
            case 2: rotconv_max_kernel<2><<<grid, 256, 0, stream>>>(x, rw, out, first); break;
            default: rotconv_max_kernel<1><<<grid, 256, 0, stream>>>(x, rw, out, first); break;
        }
        first = 0;
    }
}